// Round 1
// baseline (216.811 us; speedup 1.0000x reference)
//
#include <hip/hip_runtime.h>
#include <hip/hip_bf16.h>

// Z[b,w,t] = sum_c Q[b,w,c] * (K[b,w+t,c] + bias[c,t])
// B=16, T=1024, C=128, K has 2T-1=2047 rows.
//
// Per block: output tile BW x BT at (b, w0, t0).
//   S[i,s]  = Q[w0+i] . K[w0+t0+s]   (band scores, s in [0, BW+BT-1))
//   Zb[i,j] = Q[w0+i] . bias[:, t0+j]
//   Z[i,j]  = S[i, i+j] + Zb[i,j]
// S via MFMA into LDS; Zb via MFMA kept in regs; fused gather+store.

#define B_    16
#define T_    1024
#define C_    128
#define KT_   2047

#define BW    32      // w rows per block
#define BT    64      // t cols per block
#define KROWS 96      // BW + BT (band rows staged; last row unused, zero-padded)
#define LDB   136     // bf16 LDS row stride (128 + 8 pad -> conflict-free b128 reads)
#define SS_LD 98      // f32 S-tile stride (96 + 2 pad)

typedef short bf16x8 __attribute__((ext_vector_type(8)));
typedef float f32x4  __attribute__((ext_vector_type(4)));

__device__ __forceinline__ unsigned short f2bf(float f) {
  // round-to-nearest-even f32 -> bf16
  unsigned int u = __float_as_uint(f);
  u += 0x7FFFu + ((u >> 16) & 1u);
  return (unsigned short)(u >> 16);
}

__global__ __launch_bounds__(256) void swmm_kernel(
    const float* __restrict__ Q, const float* __restrict__ K,
    const float* __restrict__ bias, float* __restrict__ out) {
  __shared__ __align__(16) unsigned short Qs[BW * LDB];
  __shared__ __align__(16) unsigned short Ks[KROWS * LDB];
  __shared__ __align__(16) unsigned short Bs[BT * LDB];
  __shared__ __align__(16) float Ss[BW * SS_LD];

  const int b   = blockIdx.z;
  const int w0  = blockIdx.y * BW;
  const int t0  = blockIdx.x * BT;
  const int kbase = w0 + t0;
  const int tid = threadIdx.x;

  // ---- stage Q tile: BW x 128 f32 -> bf16 ----
  {
    const float4* src = (const float4*)(Q + (size_t)(b * T_ + w0) * C_);
    for (int v = tid; v < BW * (C_ / 4); v += 256) {
      int r = v >> 5, cc = v & 31;
      float4 q = src[r * 32 + cc];
      unsigned short* d = &Qs[r * LDB + (cc << 2)];
      d[0] = f2bf(q.x); d[1] = f2bf(q.y); d[2] = f2bf(q.z); d[3] = f2bf(q.w);
    }
  }
  // ---- stage K band rows kbase .. kbase+KROWS-1 (clamp: last row may be OOB, unused) ----
  {
    for (int v = tid; v < KROWS * (C_ / 4); v += 256) {
      int r = v >> 5, cc = v & 31;
      int g = kbase + r;
      float4 kv = make_float4(0.f, 0.f, 0.f, 0.f);
      if (g < KT_) kv = ((const float4*)(K + ((size_t)b * KT_ + g) * C_))[cc];
      unsigned short* d = &Ks[r * LDB + (cc << 2)];
      d[0] = f2bf(kv.x); d[1] = f2bf(kv.y); d[2] = f2bf(kv.z); d[3] = f2bf(kv.w);
    }
  }
  // ---- stage bias transposed: Bs[j][c] = bias[c][t0+j] ----
  {
    for (int v = tid; v < C_ * (BT / 4); v += 256) {
      int c = v >> 4, jj = v & 15;
      float4 bv = ((const float4*)(bias + (size_t)c * T_ + t0))[jj];
      int j4 = jj << 2;
      Bs[(j4 + 0) * LDB + c] = f2bf(bv.x);
      Bs[(j4 + 1) * LDB + c] = f2bf(bv.y);
      Bs[(j4 + 2) * LDB + c] = f2bf(bv.z);
      Bs[(j4 + 3) * LDB + c] = f2bf(bv.w);
    }
  }
  __syncthreads();

  const int wv    = tid >> 6;
  const int lane  = tid & 63;
  const int frow  = lane & 15;        // fragment row (m or n within 16-tile)
  const int koff  = (lane >> 4) * 8;  // k offset within a 32-wide K step
  const int drow4 = (lane >> 4) * 4;  // C/D: row = quad*4 + reg
  const int dcol  = lane & 15;        // C/D: col = lane & 15

  const int NS = KROWS / 16;          // 6 S n-tiles per m-band

  // ---- S band tiles: 2 m-bands x 6 n-tiles = 12 tiles, 3 per wave ----
  for (int s = wv; s < 2 * NS; s += 4) {
    int mb = s / NS, nn = s % NS;
    int m0 = mb * 16, n0 = nn * 16;
    const unsigned short* arow = &Qs[(m0 + frow) * LDB + koff];
    const unsigned short* brow = &Ks[(n0 + frow) * LDB + koff];
    f32x4 acc = {0.f, 0.f, 0.f, 0.f};
#pragma unroll
    for (int k0 = 0; k0 < C_; k0 += 32) {
      bf16x8 a  = *(const bf16x8*)(arow + k0);
      bf16x8 bb = *(const bf16x8*)(brow + k0);
      acc = __builtin_amdgcn_mfma_f32_16x16x32_bf16(a, bb, acc, 0, 0, 0);
    }
#pragma unroll
    for (int r = 0; r < 4; ++r)
      Ss[(m0 + drow4 + r) * SS_LD + n0 + dcol] = acc[r];
  }

  // ---- bias GEMM tiles: 2 m-bands x 4 n-tiles = 8 tiles, 2 per wave (static) ----
  f32x4 bacc[2];
#pragma unroll
  for (int q = 0; q < 2; ++q) {
    int idx = wv + q * 4;             // 0..7
    int m0 = (idx >> 2) * 16, j0 = (idx & 3) * 16;
    const unsigned short* arow = &Qs[(m0 + frow) * LDB + koff];
    const unsigned short* brow = &Bs[(j0 + frow) * LDB + koff];
    f32x4 acc = {0.f, 0.f, 0.f, 0.f};
#pragma unroll
    for (int k0 = 0; k0 < C_; k0 += 32) {
      bf16x8 a  = *(const bf16x8*)(arow + k0);
      bf16x8 bb = *(const bf16x8*)(brow + k0);
      acc = __builtin_amdgcn_mfma_f32_16x16x32_bf16(a, bb, acc, 0, 0, 0);
    }
    bacc[q] = acc;
  }
  __syncthreads();

  // ---- fused epilogue: Z[i,j] = bias_acc + S[i, i+j] ----
#pragma unroll
  for (int q = 0; q < 2; ++q) {
    int idx = wv + q * 4;
    int m0 = (idx >> 2) * 16, j0 = (idx & 3) * 16;
#pragma unroll
    for (int r = 0; r < 4; ++r) {
      int i = m0 + drow4 + r;         // row within [0, BW)
      int j = j0 + dcol;              // col within [0, BT)
      float z = bacc[q][r] + Ss[i * SS_LD + i + j];
      out[(size_t)(b * T_ + w0 + i) * T_ + t0 + j] = z;
    }
  }
}

extern "C" void kernel_launch(void* const* d_in, const int* in_sizes, int n_in,
                              void* d_out, int out_size, void* d_ws, size_t ws_size,
                              hipStream_t stream) {
  const float* Q    = (const float*)d_in[0];
  const float* K    = (const float*)d_in[1];
  const float* bias = (const float*)d_in[2];
  float* out = (float*)d_out;
  dim3 grid(T_ / BT, T_ / BW, B_);   // (16, 32, 16) = 8192 blocks
  swmm_kernel<<<grid, dim3(256), 0, stream>>>(Q, K, bias, out);
}

// Round 2
// 122.093 us; speedup vs baseline: 1.7758x; 1.7758x over previous
//
#include <hip/hip_runtime.h>
#include <hip/hip_bf16.h>

// Z[b,w,t] = sum_c Q[b,w,c] * (K[b,w+t,c] + bias[c,t])
// B=16, T=1024, C=128, K has 2T-1=2047 rows.
//
// Round 2: pre-pass converts Q,K->bf16 and bias->bf16 transposed in d_ws.
// Main kernel stages via global_load_lds (16B) into XOR-swizzled unpadded LDS,
// computes S band + bias GEMM with mfma_f32_16x16x32_bf16, fused diag gather.

#define B_    16
#define T_    1024
#define C_    128
#define KT_   2047

#define BW    32
#define BT    64
#define KROWS 96
#define SS_LD 98

typedef unsigned short ushort_t;
typedef short bf16x8 __attribute__((ext_vector_type(8)));
typedef float f32x4  __attribute__((ext_vector_type(4)));

__device__ __forceinline__ unsigned short f2bf(float f) {
  unsigned int u = __float_as_uint(f);
  u += 0x7FFFu + ((u >> 16) & 1u);
  return (unsigned short)(u >> 16);
}

typedef const __attribute__((address_space(1))) unsigned int* gas_ptr;
typedef __attribute__((address_space(3))) unsigned int* las_ptr;
__device__ __forceinline__ void async_copy16(const void* g, void* l) {
  __builtin_amdgcn_global_load_lds((gas_ptr)g, (las_ptr)l, 16, 0, 0);
}

// swizzled fragment pointer: chunk kc (8 bf16) of LDS row `row`
__device__ __forceinline__ const bf16x8* frag(const ushort_t* t, int row, int kc) {
  return (const bf16x8*)(t + (((row << 4) + (kc ^ (row & 7))) << 3));
}

// ---------------- pre-pass: f32 -> bf16 (+ bias transpose) ----------------
#define QN4 524288    // 16*1024*128/4
#define KN4 1048064   // 16*2047*128/4
#define BN4 32768     // 128*1024/4

__global__ __launch_bounds__(256) void prepass(
    const float* __restrict__ Q, const float* __restrict__ K,
    const float* __restrict__ bias, ushort_t* __restrict__ Qb,
    ushort_t* __restrict__ Kb, ushort_t* __restrict__ bT) {
  int idx = blockIdx.x * 256 + threadIdx.x;
  if (idx < QN4) {
    float4 v = ((const float4*)Q)[idx];
    ((ushort4*)Qb)[idx] = make_ushort4(f2bf(v.x), f2bf(v.y), f2bf(v.z), f2bf(v.w));
  } else if (idx < QN4 + KN4) {
    int i = idx - QN4;
    float4 v = ((const float4*)K)[i];
    ((ushort4*)Kb)[i] = make_ushort4(f2bf(v.x), f2bf(v.y), f2bf(v.z), f2bf(v.w));
  } else if (idx < QN4 + KN4 + BN4) {
    int i = idx - (QN4 + KN4);
    int c = i >> 8;           // 0..127
    int g = i & 255;          // group of 4 along t
    float4 v = ((const float4*)(bias + c * T_))[g];
    int t = g << 2;
    bT[(t + 0) * C_ + c] = f2bf(v.x);
    bT[(t + 1) * C_ + c] = f2bf(v.y);
    bT[(t + 2) * C_ + c] = f2bf(v.z);
    bT[(t + 3) * C_ + c] = f2bf(v.w);
  }
}

// ---------------- main kernel ----------------
// LDS rows (swizzled, 128 bf16 = 16 chunks each):
//   rows 0..31   : Q tile
//   rows 32..127 : K band (96 rows)
//   rows 128..191: bias^T tile (overlaid by f32 Ss after bias phase)
__global__ __launch_bounds__(256) void swmm_main(
    const ushort_t* __restrict__ Qb, const ushort_t* __restrict__ Kb,
    const ushort_t* __restrict__ bT, float* __restrict__ out) {
  __shared__ __align__(16) ushort_t tile[3072 * 8];   // 48 KB

  const int b  = blockIdx.z;
  const int w0 = blockIdx.y * BW;
  const int t0 = blockIdx.x * BT;
  const int kbase = w0 + t0;
  const int tid = threadIdx.x;
  const int wv = tid >> 6, lane = tid & 63;

  // ---- stage: 3072 slots of 16B, 12 segments of 256 ----
#pragma unroll
  for (int seg = 0; seg < 12; ++seg) {
    int slot = seg * 256 + tid;
    int r = slot >> 4;                      // LDS row 0..191
    int c = (slot & 15) ^ (r & 7);          // source chunk (XOR swizzle)
    const ushort_t* g;
    if (seg < 2) {
      g = Qb + (((size_t)(b * T_ + w0 + r)) << 7) + (c << 3);
    } else if (seg < 8) {
      int gk = kbase + (r - 32);
      if (gk > KT_ - 1) gk = KT_ - 1;       // row 95 never consumed; clamp addr
      g = Kb + ((size_t)b * KT_ + gk) * C_ + (c << 3);
    } else {
      g = bT + (((size_t)(t0 + r - 128)) << 7) + (c << 3);
    }
    async_copy16(g, &tile[(size_t)(seg * 256 + wv * 64) * 8]);
  }
  __syncthreads();

  const int frow = lane & 15;
  const int quad = lane >> 4;
  const int drow4 = quad * 4;

  // ---- phase 1: bias GEMM, 8 tiles (2 per wave), kept in regs ----
  f32x4 bacc[2];
#pragma unroll
  for (int q = 0; q < 2; ++q) {
    int idx = wv + q * 4;
    int m0 = (idx >> 2) * 16, j0 = (idx & 3) * 16;
    f32x4 acc = {0.f, 0.f, 0.f, 0.f};
#pragma unroll
    for (int kk = 0; kk < 4; ++kk) {
      int kc = kk * 4 + quad;
      bf16x8 a  = *frag(tile, m0 + frow, kc);
      bf16x8 bb = *frag(tile, 128 + j0 + frow, kc);
      acc = __builtin_amdgcn_mfma_f32_16x16x32_bf16(a, bb, acc, 0, 0, 0);
    }
    bacc[q] = acc;
  }
  __syncthreads();   // all waves done reading bias region

  // ---- phase 2: S band tiles (12, 3 per wave) -> f32 Ss overlaid on bias ----
  float* Ss = (float*)&tile[2048 * 8];
#pragma unroll
  for (int q = 0; q < 3; ++q) {
    int s = wv + q * 4;                     // 0..11
    int mb = s / 6, nn = s % 6;
    int m0 = mb * 16, n0 = nn * 16;
    f32x4 acc = {0.f, 0.f, 0.f, 0.f};
#pragma unroll
    for (int kk = 0; kk < 4; ++kk) {
      int kc = kk * 4 + quad;
      bf16x8 a  = *frag(tile, m0 + frow, kc);
      bf16x8 bb = *frag(tile, 32 + n0 + frow, kc);
      acc = __builtin_amdgcn_mfma_f32_16x16x32_bf16(a, bb, acc, 0, 0, 0);
    }
#pragma unroll
    for (int r = 0; r < 4; ++r)
      Ss[(m0 + drow4 + r) * SS_LD + n0 + frow] = acc[r];
  }
  __syncthreads();

  // ---- epilogue: Z[i,j] = bias_acc + S[i, i+j] ----
#pragma unroll
  for (int q = 0; q < 2; ++q) {
    int idx = wv + q * 4;
    int m0 = (idx >> 2) * 16, j0 = (idx & 3) * 16;
#pragma unroll
    for (int r = 0; r < 4; ++r) {
      int i = m0 + drow4 + r;
      int j = j0 + frow;
      out[(size_t)(b * T_ + w0 + i) * T_ + t0 + j] = bacc[q][r] + Ss[i * SS_LD + i + j];
    }
  }
}

// ---------------- fallback (round-1 kernel) if ws too small ----------------
#define LDB 136
__global__ __launch_bounds__(256) void swmm_fallback(
    const float* __restrict__ Q, const float* __restrict__ K,
    const float* __restrict__ bias, float* __restrict__ out) {
  __shared__ __align__(16) unsigned short Qs[BW * LDB];
  __shared__ __align__(16) unsigned short Ks[KROWS * LDB];
  __shared__ __align__(16) unsigned short Bs[BT * LDB];
  __shared__ __align__(16) float Ss[BW * SS_LD];

  const int b   = blockIdx.z;
  const int w0  = blockIdx.y * BW;
  const int t0  = blockIdx.x * BT;
  const int kbase = w0 + t0;
  const int tid = threadIdx.x;

  {
    const float4* src = (const float4*)(Q + (size_t)(b * T_ + w0) * C_);
    for (int v = tid; v < BW * (C_ / 4); v += 256) {
      int r = v >> 5, cc = v & 31;
      float4 q = src[r * 32 + cc];
      unsigned short* d = &Qs[r * LDB + (cc << 2)];
      d[0] = f2bf(q.x); d[1] = f2bf(q.y); d[2] = f2bf(q.z); d[3] = f2bf(q.w);
    }
  }
  {
    for (int v = tid; v < KROWS * (C_ / 4); v += 256) {
      int r = v >> 5, cc = v & 31;
      int g = kbase + r;
      float4 kv = make_float4(0.f, 0.f, 0.f, 0.f);
      if (g < KT_) kv = ((const float4*)(K + ((size_t)b * KT_ + g) * C_))[cc];
      unsigned short* d = &Ks[r * LDB + (cc << 2)];
      d[0] = f2bf(kv.x); d[1] = f2bf(kv.y); d[2] = f2bf(kv.z); d[3] = f2bf(kv.w);
    }
  }
  {
    for (int v = tid; v < C_ * (BT / 4); v += 256) {
      int c = v >> 4, jj = v & 15;
      float4 bv = ((const float4*)(bias + (size_t)c * T_ + t0))[jj];
      int j4 = jj << 2;
      Bs[(j4 + 0) * LDB + c] = f2bf(bv.x);
      Bs[(j4 + 1) * LDB + c] = f2bf(bv.y);
      Bs[(j4 + 2) * LDB + c] = f2bf(bv.z);
      Bs[(j4 + 3) * LDB + c] = f2bf(bv.w);
    }
  }
  __syncthreads();

  const int wv    = tid >> 6;
  const int lane  = tid & 63;
  const int frow  = lane & 15;
  const int koff  = (lane >> 4) * 8;
  const int drow4 = (lane >> 4) * 4;
  const int NS = KROWS / 16;

  for (int s = wv; s < 2 * NS; s += 4) {
    int mb = s / NS, nn = s % NS;
    int m0 = mb * 16, n0 = nn * 16;
    const unsigned short* arow = &Qs[(m0 + frow) * LDB + koff];
    const unsigned short* brow = &Ks[(n0 + frow) * LDB + koff];
    f32x4 acc = {0.f, 0.f, 0.f, 0.f};
#pragma unroll
    for (int k0 = 0; k0 < C_; k0 += 32) {
      bf16x8 a  = *(const bf16x8*)(arow + k0);
      bf16x8 bb = *(const bf16x8*)(brow + k0);
      acc = __builtin_amdgcn_mfma_f32_16x16x32_bf16(a, bb, acc, 0, 0, 0);
    }
#pragma unroll
    for (int r = 0; r < 4; ++r)
      Ss[(m0 + drow4 + r) * SS_LD + n0 + frow] = acc[r];
  }

  f32x4 bacc[2];
#pragma unroll
  for (int q = 0; q < 2; ++q) {
    int idx = wv + q * 4;
    int m0 = (idx >> 2) * 16, j0 = (idx & 3) * 16;
    const unsigned short* arow = &Qs[(m0 + frow) * LDB + koff];
    const unsigned short* brow = &Bs[(j0 + frow) * LDB + koff];
    f32x4 acc = {0.f, 0.f, 0.f, 0.f};
#pragma unroll
    for (int k0 = 0; k0 < C_; k0 += 32) {
      bf16x8 a  = *(const bf16x8*)(arow + k0);
      bf16x8 bb = *(const bf16x8*)(brow + k0);
      acc = __builtin_amdgcn_mfma_f32_16x16x32_bf16(a, bb, acc, 0, 0, 0);
    }
    bacc[q] = acc;
  }
  __syncthreads();

#pragma unroll
  for (int q = 0; q < 2; ++q) {
    int idx = wv + q * 4;
    int m0 = (idx >> 2) * 16, j0 = (idx & 3) * 16;
#pragma unroll
    for (int r = 0; r < 4; ++r) {
      int i = m0 + drow4 + r;
      int j = j0 + frow;
      out[(size_t)(b * T_ + w0 + i) * T_ + t0 + j] = bacc[q][r] + Ss[i * SS_LD + i + j];
    }
  }
}

extern "C" void kernel_launch(void* const* d_in, const int* in_sizes, int n_in,
                              void* d_out, int out_size, void* d_ws, size_t ws_size,
                              hipStream_t stream) {
  const float* Q    = (const float*)d_in[0];
  const float* K    = (const float*)d_in[1];
  const float* bias = (const float*)d_in[2];
  float* out = (float*)d_out;

  const size_t QB = (size_t)B_ * T_ * C_ * 2;        // 4 MB
  const size_t KB = (size_t)B_ * KT_ * C_ * 2;       // 8.38 MB
  const size_t TB = (size_t)T_ * C_ * 2;             // 0.25 MB
  dim3 grid(T_ / BT, T_ / BW, B_);                   // 8192 blocks

  if (ws_size >= QB + KB + TB) {
    ushort_t* Qb = (ushort_t*)d_ws;
    ushort_t* Kb = (ushort_t*)((char*)d_ws + QB);
    ushort_t* bT = (ushort_t*)((char*)d_ws + QB + KB);
    prepass<<<(QN4 + KN4 + BN4) / 256, 256, 0, stream>>>(Q, K, bias, Qb, Kb, bT);
    swmm_main<<<grid, dim3(256), 0, stream>>>(Qb, Kb, bT, out);
  } else {
    swmm_fallback<<<grid, dim3(256), 0, stream>>>(Q, K, bias, out);
  }
}